// Round 2
// baseline (3116.042 us; speedup 1.0000x reference)
//
#include <hip/hip_runtime.h>

#define SEQ  4096
#define HIDN 1280
#define NHD  16
#define HDD  80
#define HLF  40
#define NQKV 3840

// =============================================================================
// GEMM (NT): C[M][N] = A[M][K] @ W[N][K]^T + bias[N]
// 128x128 tile, 256 threads, 8x8 microtile. STRIDED ownership both axes:
// thread (ty,tx) owns rows ty+16*i, cols tx+16*j. With pad=36 (f4-aligned),
// a4 reads are conflict-free (ty rows 4 banks apart, disjoint b128 spans),
// b4 reads 2-way (free per m136).
// =============================================================================
__global__ __launch_bounds__(256) void gemm_nt(
    const float* __restrict__ A, const float* __restrict__ W,
    const float* __restrict__ bias, float* __restrict__ C,
    int M, int N, int K)
{
  __shared__ float As[128][36];
  __shared__ float Ws[128][36];
  const int m0 = blockIdx.y * 128;
  const int n0 = blockIdx.x * 128;
  const int tid = threadIdx.x;
  const int ty = tid >> 4;   // 0..15 -> rows ty+16*i
  const int tx = tid & 15;   // 0..15 -> cols tx+16*j

  float acc[8][8];
#pragma unroll
  for (int i = 0; i < 8; ++i)
#pragma unroll
    for (int j = 0; j < 8; ++j) acc[i][j] = 0.f;

  for (int k0 = 0; k0 < K; k0 += 32) {
    __syncthreads();
#pragma unroll
    for (int r = 0; r < 4; ++r) {
      int t = tid + r * 256;          // 1024 f4 tasks/matrix: 128 rows x 8 f4
      int row = t >> 3, c4 = t & 7;
      *(float4*)&As[row][4*c4] = *(const float4*)(A + (size_t)(m0+row)*K + k0 + 4*c4);
      *(float4*)&Ws[row][4*c4] = *(const float4*)(W + (size_t)(n0+row)*K + k0 + 4*c4);
    }
    __syncthreads();
#pragma unroll
    for (int k4 = 0; k4 < 8; ++k4) {
      float4 a4[8], b4[8];
#pragma unroll
      for (int i = 0; i < 8; ++i) a4[i] = *(const float4*)&As[ty+16*i][4*k4];
#pragma unroll
      for (int j = 0; j < 8; ++j) b4[j] = *(const float4*)&Ws[tx+16*j][4*k4];
#pragma unroll
      for (int i = 0; i < 8; ++i)
#pragma unroll
        for (int j = 0; j < 8; ++j) {
          acc[i][j] += a4[i].x * b4[j].x;
          acc[i][j] += a4[i].y * b4[j].y;
          acc[i][j] += a4[i].z * b4[j].z;
          acc[i][j] += a4[i].w * b4[j].w;
        }
    }
  }

  float bj[8];
#pragma unroll
  for (int j = 0; j < 8; ++j) bj[j] = bias[n0 + tx + 16*j];
#pragma unroll
  for (int i = 0; i < 8; ++i) {
    size_t rowoff = (size_t)(m0 + ty + 16*i) * N + n0;
#pragma unroll
    for (int j = 0; j < 8; ++j)
      C[rowoff + tx + 16*j] = acc[i][j] + bj[j];
  }
}

// =============================================================================
// RoPE in-place on qkv_raw[S][3][NH][HD] (q and k only; v untouched).
// out[d]    = x[d]*cos[d]      - x[d+40]*sin[d]       (d < 40)
// out[d+40] = x[d+40]*cos[d+40] + x[d]*sin[d+40]
// Each thread owns one (s,h,d<40) pair-slot for q and k -> no hazards.
// =============================================================================
__global__ __launch_bounds__(256) void rope_inplace(
    float* __restrict__ qkv, const float* __restrict__ cosb,
    const float* __restrict__ sinb)
{
  int t = blockIdx.x * 256 + threadIdx.x;       // SEQ*NHD*HLF tasks
  if (t >= SEQ * NHD * HLF) return;
  int d = t % HLF;
  int h = (t / HLF) % NHD;
  int s = t / (HLF * NHD);

  size_t base = (size_t)s * NQKV + h * HDD;
  float q1 = qkv[base + d],          q2 = qkv[base + d + HLF];
  float k1 = qkv[base + HIDN + d],   k2 = qkv[base + HIDN + d + HLF];
  float c1 = cosb[(size_t)s*HDD + d], c2 = cosb[(size_t)s*HDD + d + HLF];
  float s1 = sinb[(size_t)s*HDD + d], s2 = sinb[(size_t)s*HDD + d + HLF];

  qkv[base + d]              = q1 * c1 - q2 * s1;
  qkv[base + d + HLF]        = q2 * c2 + q1 * s2;
  qkv[base + HIDN + d]       = k1 * c1 - k2 * s1;
  qkv[base + HIDN + d + HLF] = k2 * c2 + k1 * s2;
}

// =============================================================================
// Flash-style attention, block-diagonal segments, reading strided Q/K/V
// directly from qkv_raw[S][3][NH][HD]. One block per (head, 64-row q-tile).
// 256 threads = (ty 0..15) x (tx 0..15); score microtile rows 4*ty+i,
// cols tx+16*j; output dims tx+16*dd. Online softmax. LDS 81.9 KiB.
// =============================================================================
__global__ __launch_bounds__(256) void attn_kernel(
    const float* __restrict__ qkv, const int* __restrict__ cu, int ncu,
    float* __restrict__ out /*[SEQ][HIDN]*/)
{
  __shared__ float Qs[64][84];
  __shared__ float Ks[64][84];
  __shared__ float Vs[64][84];
  __shared__ float Ps[64][68];

  const int h  = blockIdx.y;
  const int r0 = blockIdx.x * 64;
  const int tid = threadIdx.x;
  const int ty = tid >> 4, tx = tid & 15;
  const float scale = 0.11180339887498949f;   // 80^-0.5

  // stage Q tile: 64 rows x 20 float4 (row stride NQKV in global)
#pragma unroll
  for (int r = 0; r < 5; ++r) {
    int t = tid + r * 256;
    int row = t / 20, d4 = t % 20;
    *(float4*)&Qs[row][4*d4] =
        *(const float4*)(qkv + (size_t)(r0 + row)*NQKV + h*HDD + 4*d4);
  }

  // per-row segment bounds
  int lo[4], hi[4];
#pragma unroll
  for (int i = 0; i < 4; ++i) {
    int r = r0 + 4*ty + i;
    int lo_ = 0, hi_ = SEQ;
    for (int j = 0; j + 1 < ncu; ++j)
      if (r >= cu[j] && r < cu[j+1]) { lo_ = cu[j]; hi_ = cu[j+1]; }
    lo[i] = lo_; hi[i] = hi_;
  }
  // tile-union K range
  int klo = 0, khi = SEQ;
  for (int j = 0; j + 1 < ncu; ++j) {
    if (r0      >= cu[j] && r0      < cu[j+1]) klo = cu[j];
    if (r0 + 63 >= cu[j] && r0 + 63 < cu[j+1]) khi = cu[j+1];
  }

  float m[4], l[4], o[4][5];
#pragma unroll
  for (int i = 0; i < 4; ++i) {
    m[i] = -3.0e38f; l[i] = 0.f;
#pragma unroll
    for (int dd = 0; dd < 5; ++dd) o[i][dd] = 0.f;
  }

  for (int kb = klo; kb < khi; kb += 64) {
    __syncthreads();   // previous PV done before restaging
#pragma unroll
    for (int r = 0; r < 5; ++r) {
      int t = tid + r * 256;
      int row = t / 20, d4 = t % 20;
      size_t g = (size_t)(kb + row)*NQKV + h*HDD + 4*d4;
      *(float4*)&Ks[row][4*d4] = *(const float4*)(qkv + g + HIDN);
      *(float4*)&Vs[row][4*d4] = *(const float4*)(qkv + g + 2*HIDN);
    }
    __syncthreads();

    // scores: s[i][j] = q_row(4ty+i) . k_col(tx+16j)
    float sc[4][4];
#pragma unroll
    for (int i = 0; i < 4; ++i)
#pragma unroll
      for (int j = 0; j < 4; ++j) sc[i][j] = 0.f;

#pragma unroll
    for (int d4 = 0; d4 < 20; ++d4) {
      float4 a4[4], b4[4];
#pragma unroll
      for (int i = 0; i < 4; ++i) a4[i] = *(const float4*)&Qs[4*ty+i][4*d4];
#pragma unroll
      for (int j = 0; j < 4; ++j) b4[j] = *(const float4*)&Ks[tx+16*j][4*d4];
#pragma unroll
      for (int i = 0; i < 4; ++i)
#pragma unroll
        for (int j = 0; j < 4; ++j) {
          sc[i][j] += a4[i].x * b4[j].x;
          sc[i][j] += a4[i].y * b4[j].y;
          sc[i][j] += a4[i].z * b4[j].z;
          sc[i][j] += a4[i].w * b4[j].w;
        }
    }

    // online softmax per row
#pragma unroll
    for (int i = 0; i < 4; ++i) {
      float mt = -3.0e38f;
      bool valid[4];
#pragma unroll
      for (int j = 0; j < 4; ++j) {
        int col = kb + tx + 16*j;
        valid[j] = (col >= lo[i]) && (col < hi[i]);
        sc[i][j] = valid[j] ? sc[i][j] * scale : -3.0e38f;
        mt = fmaxf(mt, sc[i][j]);
      }
#pragma unroll
      for (int off = 1; off < 16; off <<= 1)
        mt = fmaxf(mt, __shfl_xor(mt, off));
      float mnew = fmaxf(m[i], mt);
      float alpha = __expf(m[i] - mnew);
      float rs = 0.f;
#pragma unroll
      for (int j = 0; j < 4; ++j) {
        float p = valid[j] ? __expf(sc[i][j] - mnew) : 0.f;
        Ps[4*ty+i][tx + 16*j] = p;
        rs += p;
      }
#pragma unroll
      for (int off = 1; off < 16; off <<= 1)
        rs += __shfl_xor(rs, off);
      l[i] = l[i] * alpha + rs;
#pragma unroll
      for (int dd = 0; dd < 5; ++dd) o[i][dd] *= alpha;
      m[i] = mnew;
    }
    __syncthreads();

    // PV: o[row][dim] += sum_c P[row][c] * V[c][dim], dims owned tx+16*dd
#pragma unroll
    for (int c4 = 0; c4 < 16; ++c4) {
      float pr[4][4];
#pragma unroll
      for (int i = 0; i < 4; ++i) {
        float4 p4 = *(const float4*)&Ps[4*ty+i][4*c4];
        pr[i][0] = p4.x; pr[i][1] = p4.y; pr[i][2] = p4.z; pr[i][3] = p4.w;
      }
#pragma unroll
      for (int cc = 0; cc < 4; ++cc) {
        float vv[5];
#pragma unroll
        for (int dd = 0; dd < 5; ++dd) vv[dd] = Vs[4*c4+cc][tx + 16*dd];
#pragma unroll
        for (int i = 0; i < 4; ++i) {
          float pp = pr[i][cc];
#pragma unroll
          for (int dd = 0; dd < 5; ++dd) o[i][dd] += pp * vv[dd];
        }
      }
    }
  }

  // epilogue: normalize and write [S][HID] with head offset
#pragma unroll
  for (int i = 0; i < 4; ++i) {
    float inv = 1.f / l[i];
    size_t rowoff = (size_t)(r0 + 4*ty + i) * HIDN + h * HDD;
#pragma unroll
    for (int dd = 0; dd < 5; ++dd)
      out[rowoff + tx + 16*dd] = o[i][dd] * inv;
  }
}

// =============================================================================
// launch
// =============================================================================
extern "C" void kernel_launch(void* const* d_in, const int* in_sizes, int n_in,
                              void* d_out, int out_size, void* d_ws, size_t ws_size,
                              hipStream_t stream) {
  const float* hs     = (const float*)d_in[0];
  const float* cosb   = (const float*)d_in[1];
  const float* sinb   = (const float*)d_in[2];
  const float* qkv_w  = (const float*)d_in[3];
  const float* qkv_b  = (const float*)d_in[4];
  const float* proj_w = (const float*)d_in[5];
  const float* proj_b = (const float*)d_in[6];
  const int*   cu     = (const int*)d_in[7];
  const int    ncu    = in_sizes[7];
  float* out = (float*)d_out;

  float* ws = (float*)d_ws;
  float* qkv_raw  = ws;                          // SEQ*NQKV  = 15,728,640 f (63 MB)
  float* attn_out = ws + (size_t)SEQ * NQKV;     // SEQ*HIDN  =  5,242,880 f (21 MB)

  // 1) QKV = hs @ qkv_w^T + qkv_b
  gemm_nt<<<dim3(NQKV/128, SEQ/128), 256, 0, stream>>>(hs, qkv_w, qkv_b, qkv_raw,
                                                       SEQ, NQKV, HIDN);
  // 2) RoPE in place on q,k
  {
    int tasks = SEQ * NHD * HLF;
    rope_inplace<<<(tasks + 255)/256, 256, 0, stream>>>(qkv_raw, cosb, sinb);
  }
  // 3) segment-blocked flash attention -> attn_out [SEQ][HID]
  attn_kernel<<<dim3(SEQ/64, NHD), 256, 0, stream>>>(qkv_raw, cu, ncu, attn_out);
  // 4) out = attn_out @ proj_w^T + proj_b
  gemm_nt<<<dim3(HIDN/128, SEQ/128), 256, 0, stream>>>(attn_out, proj_w, proj_b, out,
                                                       SEQ, HIDN, HIDN);
}

// Round 3
// 1409.503 us; speedup vs baseline: 2.2107x; 2.2107x over previous
//
#include <hip/hip_runtime.h>
#include <hip/hip_bf16.h>

#define SEQ  4096
#define HIDN 1280
#define NHD  16
#define HDD  80
#define HLF  40
#define NQKV 3840

typedef __attribute__((ext_vector_type(8))) short short8v;  // 8 bf16 = 4 VGPR
typedef __attribute__((ext_vector_type(4))) float f32x4;
typedef unsigned short u16;
typedef unsigned int u32;

// round-to-nearest-even f32 -> bf16 bits
__device__ inline u16 f2b(float f) {
  union { float f; u32 u; } x; x.f = f;
  u32 r = x.u + 0x7fff + ((x.u >> 16) & 1);
  return (u16)(r >> 16);
}

// =============================================================================
// GEMM (NT) fp32: C[M][N] = A[M][K] @ W[N][K]^T + bias[N]. 128x128 tile,
// 256 threads, 8x8 microtile, strided ownership (unchanged from R1).
// =============================================================================
__global__ __launch_bounds__(256) void gemm_nt(
    const float* __restrict__ A, const float* __restrict__ W,
    const float* __restrict__ bias, float* __restrict__ C,
    int M, int N, int K)
{
  __shared__ float As[128][36];
  __shared__ float Ws[128][36];
  const int m0 = blockIdx.y * 128;
  const int n0 = blockIdx.x * 128;
  const int tid = threadIdx.x;
  const int ty = tid >> 4;
  const int tx = tid & 15;

  float acc[8][8];
#pragma unroll
  for (int i = 0; i < 8; ++i)
#pragma unroll
    for (int j = 0; j < 8; ++j) acc[i][j] = 0.f;

  for (int k0 = 0; k0 < K; k0 += 32) {
    __syncthreads();
#pragma unroll
    for (int r = 0; r < 4; ++r) {
      int t = tid + r * 256;
      int row = t >> 3, c4 = t & 7;
      *(float4*)&As[row][4*c4] = *(const float4*)(A + (size_t)(m0+row)*K + k0 + 4*c4);
      *(float4*)&Ws[row][4*c4] = *(const float4*)(W + (size_t)(n0+row)*K + k0 + 4*c4);
    }
    __syncthreads();
#pragma unroll
    for (int k4 = 0; k4 < 8; ++k4) {
      float4 a4[8], b4[8];
#pragma unroll
      for (int i = 0; i < 8; ++i) a4[i] = *(const float4*)&As[ty+16*i][4*k4];
#pragma unroll
      for (int j = 0; j < 8; ++j) b4[j] = *(const float4*)&Ws[tx+16*j][4*k4];
#pragma unroll
      for (int i = 0; i < 8; ++i)
#pragma unroll
        for (int j = 0; j < 8; ++j) {
          acc[i][j] += a4[i].x * b4[j].x;
          acc[i][j] += a4[i].y * b4[j].y;
          acc[i][j] += a4[i].z * b4[j].z;
          acc[i][j] += a4[i].w * b4[j].w;
        }
    }
  }

  float bj[8];
#pragma unroll
  for (int j = 0; j < 8; ++j) bj[j] = bias[n0 + tx + 16*j];
#pragma unroll
  for (int i = 0; i < 8; ++i) {
    size_t rowoff = (size_t)(m0 + ty + 16*i) * N + n0;
#pragma unroll
    for (int j = 0; j < 8; ++j)
      C[rowoff + tx + 16*j] = acc[i][j] + bj[j];
  }
}

// =============================================================================
// RoPE in-place on qkv_raw[S][3][NH][HD] (q,k only) — unchanged from R1.
// =============================================================================
__global__ __launch_bounds__(256) void rope_inplace(
    float* __restrict__ qkv, const float* __restrict__ cosb,
    const float* __restrict__ sinb)
{
  int t = blockIdx.x * 256 + threadIdx.x;
  if (t >= SEQ * NHD * HLF) return;
  int d = t % HLF;
  int h = (t / HLF) % NHD;
  int s = t / (HLF * NHD);

  size_t base = (size_t)s * NQKV + h * HDD;
  float q1 = qkv[base + d],          q2 = qkv[base + d + HLF];
  float k1 = qkv[base + HIDN + d],   k2 = qkv[base + HIDN + d + HLF];
  float c1 = cosb[(size_t)s*HDD + d], c2 = cosb[(size_t)s*HDD + d + HLF];
  float s1 = sinb[(size_t)s*HDD + d], s2 = sinb[(size_t)s*HDD + d + HLF];

  qkv[base + d]              = q1 * c1 - q2 * s1;
  qkv[base + d + HLF]        = q2 * c2 + q1 * s2;
  qkv[base + HIDN + d]       = k1 * c1 - k2 * s1;
  qkv[base + HIDN + d + HLF] = k2 * c2 + k1 * s2;
}

// =============================================================================
// bf16-MFMA flash attention, block-diagonal segments.
// Block = (head, 64 q-rows), 256 thr = 4 waves; wave owns 16 q-rows.
// mfma_f32_16x16x32_bf16; dims padded 80->96 (zeroed cols).
// Fragment maps (m89-verified): A row=l&15,k=(l>>4)*8+j; B col=l&15,k=same;
// C col=l&15,row=4*(l>>4)+reg.
// LDS: Qs/Ks [64][104] bf16, Vt [80][72] bf16 (transposed), Pl [4][16][72].
// Total 46.3 KiB -> 3 blocks/CU (37.5% occ).
// =============================================================================
__global__ __launch_bounds__(256) void attn_mfma(
    const float* __restrict__ qkv, const int* __restrict__ cu, int ncu,
    float* __restrict__ out /*[SEQ][HIDN]*/)
{
  __shared__ u16 Qs[64][104];
  __shared__ u16 Ks[64][104];
  __shared__ u16 Vt[80][72];      // [dim][krow]
  __shared__ u16 Pl[4][16][72];   // per-wave P, [qrow][kcol]

  const int h   = blockIdx.y;
  const int r0  = blockIdx.x * 64;
  const int tid = threadIdx.x;
  const int w    = tid >> 6;
  const int lane = tid & 63;
  const int lg   = lane >> 4;     // 16-lane group
  const int ln   = lane & 15;
  const float scale = 0.11180339887498949f;   // 80^-0.5

  // zero the padded dim cols (80..103) of Qs and Ks once
  for (int t = tid; t < 64*24; t += 256) {
    int row = t / 24, c = 80 + (t % 24);
    Qs[row][c] = 0; Ks[row][c] = 0;
  }
  // stage Q tile -> bf16 (coalesced reads, contiguous 8B writes)
  for (int t = tid; t < 64*20; t += 256) {
    int row = t / 20, d4 = (t % 20) * 4;
    float4 v = *(const float4*)(qkv + (size_t)(r0+row)*NQKV + h*HDD + d4);
    ushort4 b; b.x = f2b(v.x); b.y = f2b(v.y); b.z = f2b(v.z); b.w = f2b(v.w);
    *(ushort4*)&Qs[row][d4] = b;
  }

  // per-(reg) segment bounds for this lane's 4 rows
  int lo[4], hi[4];
#pragma unroll
  for (int q = 0; q < 4; ++q) {
    int r = r0 + w*16 + 4*lg + q;
    int lo_ = 0, hi_ = SEQ;
    for (int j = 0; j + 1 < ncu; ++j)
      if (r >= cu[j] && r < cu[j+1]) { lo_ = cu[j]; hi_ = cu[j+1]; }
    lo[q] = lo_; hi[q] = hi_;
  }
  int klo = 0, khi = SEQ;
  for (int j = 0; j + 1 < ncu; ++j) {
    if (r0      >= cu[j] && r0      < cu[j+1]) klo = cu[j];
    if (r0 + 63 >= cu[j] && r0 + 63 < cu[j+1]) khi = cu[j+1];
  }

  f32x4 oacc[5];
#pragma unroll
  for (int vt = 0; vt < 5; ++vt) oacc[vt] = (f32x4){0.f,0.f,0.f,0.f};
  float m_[4] = {-3.0e38f,-3.0e38f,-3.0e38f,-3.0e38f};
  float l_[4] = {0.f,0.f,0.f,0.f};

  for (int kb = klo; kb < khi; kb += 64) {
    __syncthreads();   // prev tile's QK^T/PV reads done before restage
    // stage K (coalesced reads, contiguous 8B LDS writes)
    for (int t = tid; t < 64*20; t += 256) {
      int row = t / 20, d4 = (t % 20) * 4;
      int gr = kb + row; if (gr > SEQ-1) gr = SEQ-1;
      float4 v = *(const float4*)(qkv + (size_t)gr*NQKV + h*HDD + HIDN + d4);
      ushort4 b; b.x = f2b(v.x); b.y = f2b(v.y); b.z = f2b(v.z); b.w = f2b(v.w);
      *(ushort4*)&Ks[row][d4] = b;
    }
    // stage V transposed (row=t%64: strided global reads [L3-resident],
    // conflict-free scalar LDS writes: 64 rows -> 32 banks 2-way)
    for (int t = tid; t < 64*20; t += 256) {
      int row = t & 63, d4 = (t >> 6) * 4;
      int gr = kb + row; if (gr > SEQ-1) gr = SEQ-1;
      float4 v = *(const float4*)(qkv + (size_t)gr*NQKV + h*HDD + 2*HIDN + d4);
      Vt[d4+0][row] = f2b(v.x);
      Vt[d4+1][row] = f2b(v.y);
      Vt[d4+2][row] = f2b(v.z);
      Vt[d4+3][row] = f2b(v.w);
    }
    __syncthreads();

    // ---- QK^T: sc[n][reg] = S[4*lg+reg][n*16+ln], k over 96 (3 chunks) ----
    f32x4 sc[4];
#pragma unroll
    for (int n = 0; n < 4; ++n) sc[n] = (f32x4){0.f,0.f,0.f,0.f};
#pragma unroll
    for (int c = 0; c < 3; ++c) {
      short8v a = *(const short8v*)&Qs[w*16 + ln][c*32 + lg*8];
#pragma unroll
      for (int n = 0; n < 4; ++n) {
        short8v b = *(const short8v*)&Ks[n*16 + ln][c*32 + lg*8];
        sc[n] = __builtin_amdgcn_mfma_f32_16x16x32_bf16(a, b, sc[n], 0, 0, 0);
      }
    }

    // ---- online softmax (rows 4*lg+reg live in this 16-lane group) ----
#pragma unroll
    for (int q = 0; q < 4; ++q) {
      float mx = -3.0e38f;
#pragma unroll
      for (int n = 0; n < 4; ++n) {
        int col = kb + n*16 + ln;
        bool valid = (col >= lo[q]) & (col < hi[q]);
        float s = valid ? sc[n][q] * scale : -3.0e38f;
        sc[n][q] = s;
        mx = fmaxf(mx, s);
      }
      mx = fmaxf(mx, __shfl_xor(mx, 1));
      mx = fmaxf(mx, __shfl_xor(mx, 2));
      mx = fmaxf(mx, __shfl_xor(mx, 4));
      mx = fmaxf(mx, __shfl_xor(mx, 8));
      float mnew = fmaxf(m_[q], mx);
      float alpha = __expf(m_[q] - mnew);
      float rs = 0.f;
#pragma unroll
      for (int n = 0; n < 4; ++n) {
        int col = kb + n*16 + ln;
        bool valid = (col >= lo[q]) & (col < hi[q]);
        float p = valid ? __expf(sc[n][q] - mnew) : 0.f;
        rs += p;
        Pl[w][4*lg + q][n*16 + ln] = f2b(p);
      }
      rs += __shfl_xor(rs, 1);
      rs += __shfl_xor(rs, 2);
      rs += __shfl_xor(rs, 4);
      rs += __shfl_xor(rs, 8);
      l_[q] = l_[q] * alpha + rs;
      m_[q] = mnew;
#pragma unroll
      for (int vt = 0; vt < 5; ++vt) oacc[vt][q] *= alpha;
    }
    __syncthreads();   // P visible (same-wave, but keep ordering robust)

    // ---- PV: oacc[vt][reg] += P[16x64] @ V[64x80] (2 k-chunks, 5 v-tiles) ----
#pragma unroll
    for (int c = 0; c < 2; ++c) {
      short8v a = *(const short8v*)&Pl[w][ln][c*32 + lg*8];
#pragma unroll
      for (int vt = 0; vt < 5; ++vt) {
        short8v b = *(const short8v*)&Vt[vt*16 + ln][c*32 + lg*8];
        oacc[vt] = __builtin_amdgcn_mfma_f32_16x16x32_bf16(a, b, oacc[vt], 0, 0, 0);
      }
    }
  }

  // ---- epilogue: normalize, write fp32 [S][HID] ----
#pragma unroll
  for (int q = 0; q < 4; ++q) {
    float inv = 1.f / l_[q];
    size_t rowoff = (size_t)(r0 + w*16 + 4*lg + q) * HIDN + h * HDD;
#pragma unroll
    for (int vt = 0; vt < 5; ++vt)
      out[rowoff + vt*16 + ln] = oacc[vt][q] * inv;
  }
}

// =============================================================================
// launch
// =============================================================================
extern "C" void kernel_launch(void* const* d_in, const int* in_sizes, int n_in,
                              void* d_out, int out_size, void* d_ws, size_t ws_size,
                              hipStream_t stream) {
  const float* hs     = (const float*)d_in[0];
  const float* cosb   = (const float*)d_in[1];
  const float* sinb   = (const float*)d_in[2];
  const float* qkv_w  = (const float*)d_in[3];
  const float* qkv_b  = (const float*)d_in[4];
  const float* proj_w = (const float*)d_in[5];
  const float* proj_b = (const float*)d_in[6];
  const int*   cu     = (const int*)d_in[7];
  const int    ncu    = in_sizes[7];
  float* out = (float*)d_out;

  float* ws = (float*)d_ws;
  float* qkv_raw  = ws;                          // SEQ*NQKV f (63 MB)
  float* attn_out = ws + (size_t)SEQ * NQKV;     // SEQ*HIDN f (21 MB)

  gemm_nt<<<dim3(NQKV/128, SEQ/128), 256, 0, stream>>>(hs, qkv_w, qkv_b, qkv_raw,
                                                       SEQ, NQKV, HIDN);
  {
    int tasks = SEQ * NHD * HLF;
    rope_inplace<<<(tasks + 255)/256, 256, 0, stream>>>(qkv_raw, cosb, sinb);
  }
  attn_mfma<<<dim3(SEQ/64, NHD), 256, 0, stream>>>(qkv_raw, cu, ncu, attn_out);
  gemm_nt<<<dim3(HIDN/128, SEQ/128), 256, 0, stream>>>(attn_out, proj_w, proj_b, out,
                                                       SEQ, HIDN, HIDN);
}

// Round 5
// 594.430 us; speedup vs baseline: 5.2421x; 2.3712x over previous
//
#include <hip/hip_runtime.h>
#include <hip/hip_bf16.h>

#define SEQ  4096
#define HIDN 1280
#define NHD  16
#define HDD  80
#define HLF  40
#define NQKV 3840

typedef __attribute__((ext_vector_type(8))) short short8v;  // 8 bf16 = 4 VGPR
typedef __attribute__((ext_vector_type(4))) float f32x4;
typedef unsigned short u16;
typedef unsigned int u32;

// round-to-nearest-even f32 -> bf16 bits
__device__ inline u16 f2b(float f) {
  union { float f; u32 u; } x; x.f = f;
  u32 r = x.u + 0x7fff + ((x.u >> 16) & 1);
  return (u16)(r >> 16);
}
// truncation split: v = hi + r, hi = top-16-bit truncation (exact sub), lo = bf16(r)
__device__ inline void split2(float v, u16& h, u16& l) {
  u32 u = __float_as_uint(v);
  h = (u16)(u >> 16);
  float r = v - __uint_as_float(u & 0xffff0000u);
  l = (u16)(__float_as_uint(r) >> 16);
}

// =============================================================================
// bf16 MFMA GEMM (NT): C[M][N] = A[M][K] @ W[N][K]^T + bias[N]
// 128x128 tile, BK=64, 256 thr = 4 waves (2x2 wave grid, 64x64/wave).
// TERMS=1: plain bf16 (RNE). TERMS=3: compensated hi/lo split (~2^-16 rel).
// LDS row stride 72 shorts (144B = 4 banks offset/row) -> frag reads 2-way max.
// Fragment maps (HW-validated R3): A row=l&15,k=(l>>4)*8+j; B col=l&15,k=same;
// C col=l&15,row=4*(l>>4)+reg.
// =============================================================================
template<int TERMS>
__global__ __launch_bounds__(256, 2) void gemm_bf16(
    const float* __restrict__ A, const float* __restrict__ W,
    const float* __restrict__ bias, float* __restrict__ C,
    int M, int N, int K)
{
  constexpr bool COMP = (TERMS == 3);
  __shared__ u16 Ah[128][72];
  __shared__ u16 Bh[128][72];
  __shared__ u16 Al[COMP ? 128 : 1][COMP ? 72 : 1];
  __shared__ u16 Bl[COMP ? 128 : 1][COMP ? 72 : 1];

  const int m0 = blockIdx.y * 128;
  const int n0 = blockIdx.x * 128;
  const int tid  = threadIdx.x;
  const int w    = tid >> 6;
  const int lane = tid & 63;
  const int ln   = lane & 15;
  const int lg   = lane >> 4;
  const int wr   = w >> 1;        // wave row 0..1 -> rows wr*64..
  const int wc   = w & 1;         // wave col 0..1 -> cols wc*64..

  f32x4 acc[4][4];
#pragma unroll
  for (int i = 0; i < 4; ++i)
#pragma unroll
    for (int j = 0; j < 4; ++j) acc[i][j] = (f32x4){0.f,0.f,0.f,0.f};

  for (int k0 = 0; k0 < K; k0 += 64) {
    __syncthreads();
#pragma unroll
    for (int r = 0; r < 8; ++r) {
      int t = tid + r * 256;              // 2048 tasks: 128 rows x 16 f4
      int row = t >> 4, cc = (t & 15) * 4;
      float4 va = *(const float4*)(A + (size_t)(m0+row)*K + k0 + cc);
      float4 vb = *(const float4*)(W + (size_t)(n0+row)*K + k0 + cc);
      if (COMP) {
        ushort4 ha, la, hb, lb;
        split2(va.x, ha.x, la.x); split2(va.y, ha.y, la.y);
        split2(va.z, ha.z, la.z); split2(va.w, ha.w, la.w);
        split2(vb.x, hb.x, lb.x); split2(vb.y, hb.y, lb.y);
        split2(vb.z, hb.z, lb.z); split2(vb.w, hb.w, lb.w);
        *(ushort4*)&Ah[row][cc] = ha; *(ushort4*)&Al[row][cc] = la;
        *(ushort4*)&Bh[row][cc] = hb; *(ushort4*)&Bl[row][cc] = lb;
      } else {
        ushort4 ha, hb;
        ha.x = f2b(va.x); ha.y = f2b(va.y); ha.z = f2b(va.z); ha.w = f2b(va.w);
        hb.x = f2b(vb.x); hb.y = f2b(vb.y); hb.z = f2b(vb.z); hb.w = f2b(vb.w);
        *(ushort4*)&Ah[row][cc] = ha;
        *(ushort4*)&Bh[row][cc] = hb;
      }
    }
    __syncthreads();

#pragma unroll
    for (int s = 0; s < 2; ++s) {
      short8v ah[4], bh[4], al[4], bl[4];
#pragma unroll
      for (int i = 0; i < 4; ++i) {
        ah[i] = *(const short8v*)&Ah[wr*64 + i*16 + ln][s*32 + lg*8];
        if (COMP) al[i] = *(const short8v*)&Al[wr*64 + i*16 + ln][s*32 + lg*8];
      }
#pragma unroll
      for (int j = 0; j < 4; ++j) {
        bh[j] = *(const short8v*)&Bh[wc*64 + j*16 + ln][s*32 + lg*8];
        if (COMP) bl[j] = *(const short8v*)&Bl[wc*64 + j*16 + ln][s*32 + lg*8];
      }
#pragma unroll
      for (int i = 0; i < 4; ++i)
#pragma unroll
        for (int j = 0; j < 4; ++j) {
          acc[i][j] = __builtin_amdgcn_mfma_f32_16x16x32_bf16(ah[i], bh[j], acc[i][j], 0, 0, 0);
          if (COMP) {
            acc[i][j] = __builtin_amdgcn_mfma_f32_16x16x32_bf16(al[i], bh[j], acc[i][j], 0, 0, 0);
            acc[i][j] = __builtin_amdgcn_mfma_f32_16x16x32_bf16(ah[i], bl[j], acc[i][j], 0, 0, 0);
          }
        }
    }
  }

  float bj[4];
#pragma unroll
  for (int j = 0; j < 4; ++j) bj[j] = bias[n0 + wc*64 + j*16 + ln];
#pragma unroll
  for (int i = 0; i < 4; ++i) {
    int rowbase = m0 + wr*64 + i*16 + 4*lg;
#pragma unroll
    for (int j = 0; j < 4; ++j) {
      int col = n0 + wc*64 + j*16 + ln;
#pragma unroll
      for (int q = 0; q < 4; ++q)
        C[(size_t)(rowbase + q)*N + col] = acc[i][j][q] + bj[j];
    }
  }
}

// =============================================================================
// RoPE in-place on qkv_raw[S][3][NH][HD] (q,k only) — unchanged.
// =============================================================================
__global__ __launch_bounds__(256) void rope_inplace(
    float* __restrict__ qkv, const float* __restrict__ cosb,
    const float* __restrict__ sinb)
{
  int t = blockIdx.x * 256 + threadIdx.x;
  if (t >= SEQ * NHD * HLF) return;
  int d = t % HLF;
  int h = (t / HLF) % NHD;
  int s = t / (HLF * NHD);

  size_t base = (size_t)s * NQKV + h * HDD;
  float q1 = qkv[base + d],          q2 = qkv[base + d + HLF];
  float k1 = qkv[base + HIDN + d],   k2 = qkv[base + HIDN + d + HLF];
  float c1 = cosb[(size_t)s*HDD + d], c2 = cosb[(size_t)s*HDD + d + HLF];
  float s1 = sinb[(size_t)s*HDD + d], s2 = sinb[(size_t)s*HDD + d + HLF];

  qkv[base + d]              = q1 * c1 - q2 * s1;
  qkv[base + d + HLF]        = q2 * c2 + q1 * s2;
  qkv[base + HIDN + d]       = k1 * c1 - k2 * s1;
  qkv[base + HIDN + d + HLF] = k2 * c2 + k1 * s2;
}

// =============================================================================
// bf16-MFMA flash attention, block-diagonal segments — unchanged from R3.
// =============================================================================
__global__ __launch_bounds__(256) void attn_mfma(
    const float* __restrict__ qkv, const int* __restrict__ cu, int ncu,
    float* __restrict__ out /*[SEQ][HIDN]*/)
{
  __shared__ u16 Qs[64][104];
  __shared__ u16 Ks[64][104];
  __shared__ u16 Vt[80][72];      // [dim][krow]
  __shared__ u16 Pl[4][16][72];   // per-wave P, [qrow][kcol]

  const int h   = blockIdx.y;
  const int r0  = blockIdx.x * 64;
  const int tid = threadIdx.x;
  const int w    = tid >> 6;
  const int lane = tid & 63;
  const int lg   = lane >> 4;
  const int ln   = lane & 15;
  const float scale = 0.11180339887498949f;   // 80^-0.5

  for (int t = tid; t < 64*24; t += 256) {
    int row = t / 24, c = 80 + (t % 24);
    Qs[row][c] = 0; Ks[row][c] = 0;
  }
  for (int t = tid; t < 64*20; t += 256) {
    int row = t / 20, d4 = (t % 20) * 4;
    float4 v = *(const float4*)(qkv + (size_t)(r0+row)*NQKV + h*HDD + d4);
    ushort4 b; b.x = f2b(v.x); b.y = f2b(v.y); b.z = f2b(v.z); b.w = f2b(v.w);
    *(ushort4*)&Qs[row][d4] = b;
  }

  int lo[4], hi[4];
#pragma unroll
  for (int q = 0; q < 4; ++q) {
    int r = r0 + w*16 + 4*lg + q;
    int lo_ = 0, hi_ = SEQ;
    for (int j = 0; j + 1 < ncu; ++j)
      if (r >= cu[j] && r < cu[j+1]) { lo_ = cu[j]; hi_ = cu[j+1]; }
    lo[q] = lo_; hi[q] = hi_;
  }
  int klo = 0, khi = SEQ;
  for (int j = 0; j + 1 < ncu; ++j) {
    if (r0      >= cu[j] && r0      < cu[j+1]) klo = cu[j];
    if (r0 + 63 >= cu[j] && r0 + 63 < cu[j+1]) khi = cu[j+1];
  }

  f32x4 oacc[5];
#pragma unroll
  for (int vt = 0; vt < 5; ++vt) oacc[vt] = (f32x4){0.f,0.f,0.f,0.f};
  float m_[4] = {-3.0e38f,-3.0e38f,-3.0e38f,-3.0e38f};
  float l_[4] = {0.f,0.f,0.f,0.f};

  for (int kb = klo; kb < khi; kb += 64) {
    __syncthreads();
    for (int t = tid; t < 64*20; t += 256) {
      int row = t / 20, d4 = (t % 20) * 4;
      int gr = kb + row; if (gr > SEQ-1) gr = SEQ-1;
      float4 v = *(const float4*)(qkv + (size_t)gr*NQKV + h*HDD + HIDN + d4);
      ushort4 b; b.x = f2b(v.x); b.y = f2b(v.y); b.z = f2b(v.z); b.w = f2b(v.w);
      *(ushort4*)&Ks[row][d4] = b;
    }
    for (int t = tid; t < 64*20; t += 256) {
      int row = t & 63, d4 = (t >> 6) * 4;
      int gr = kb + row; if (gr > SEQ-1) gr = SEQ-1;
      float4 v = *(const float4*)(qkv + (size_t)gr*NQKV + h*HDD + 2*HIDN + d4);
      Vt[d4+0][row] = f2b(v.x);
      Vt[d4+1][row] = f2b(v.y);
      Vt[d4+2][row] = f2b(v.z);
      Vt[d4+3][row] = f2b(v.w);
    }
    __syncthreads();

    f32x4 sc[4];
#pragma unroll
    for (int n = 0; n < 4; ++n) sc[n] = (f32x4){0.f,0.f,0.f,0.f};
#pragma unroll
    for (int c = 0; c < 3; ++c) {
      short8v a = *(const short8v*)&Qs[w*16 + ln][c*32 + lg*8];
#pragma unroll
      for (int n = 0; n < 4; ++n) {
        short8v b = *(const short8v*)&Ks[n*16 + ln][c*32 + lg*8];
        sc[n] = __builtin_amdgcn_mfma_f32_16x16x32_bf16(a, b, sc[n], 0, 0, 0);
      }
    }

#pragma unroll
    for (int q = 0; q < 4; ++q) {
      float mx = -3.0e38f;
#pragma unroll
      for (int n = 0; n < 4; ++n) {
        int col = kb + n*16 + ln;
        bool valid = (col >= lo[q]) & (col < hi[q]);
        float s = valid ? sc[n][q] * scale : -3.0e38f;
        sc[n][q] = s;
        mx = fmaxf(mx, s);
      }
      mx = fmaxf(mx, __shfl_xor(mx, 1));
      mx = fmaxf(mx, __shfl_xor(mx, 2));
      mx = fmaxf(mx, __shfl_xor(mx, 4));
      mx = fmaxf(mx, __shfl_xor(mx, 8));
      float mnew = fmaxf(m_[q], mx);
      float alpha = __expf(m_[q] - mnew);
      float rs = 0.f;
#pragma unroll
      for (int n = 0; n < 4; ++n) {
        int col = kb + n*16 + ln;
        bool valid = (col >= lo[q]) & (col < hi[q]);
        float p = valid ? __expf(sc[n][q] - mnew) : 0.f;
        rs += p;
        Pl[w][4*lg + q][n*16 + ln] = f2b(p);
      }
      rs += __shfl_xor(rs, 1);
      rs += __shfl_xor(rs, 2);
      rs += __shfl_xor(rs, 4);
      rs += __shfl_xor(rs, 8);
      l_[q] = l_[q] * alpha + rs;
      m_[q] = mnew;
#pragma unroll
      for (int vt = 0; vt < 5; ++vt) oacc[vt][q] *= alpha;
    }
    __syncthreads();

#pragma unroll
    for (int c = 0; c < 2; ++c) {
      short8v a = *(const short8v*)&Pl[w][ln][c*32 + lg*8];
#pragma unroll
      for (int vt = 0; vt < 5; ++vt) {
        short8v b = *(const short8v*)&Vt[vt*16 + ln][c*32 + lg*8];
        oacc[vt] = __builtin_amdgcn_mfma_f32_16x16x32_bf16(a, b, oacc[vt], 0, 0, 0);
      }
    }
  }

#pragma unroll
  for (int q = 0; q < 4; ++q) {
    float inv = 1.f / l_[q];
    size_t rowoff = (size_t)(r0 + w*16 + 4*lg + q) * HIDN + h * HDD;
#pragma unroll
    for (int vt = 0; vt < 5; ++vt)
      out[rowoff + vt*16 + ln] = oacc[vt][q] * inv;
  }
}

// =============================================================================
// launch
// =============================================================================
extern "C" void kernel_launch(void* const* d_in, const int* in_sizes, int n_in,
                              void* d_out, int out_size, void* d_ws, size_t ws_size,
                              hipStream_t stream) {
  const float* hs     = (const float*)d_in[0];
  const float* cosb   = (const float*)d_in[1];
  const float* sinb   = (const float*)d_in[2];
  const float* qkv_w  = (const float*)d_in[3];
  const float* qkv_b  = (const float*)d_in[4];
  const float* proj_w = (const float*)d_in[5];
  const float* proj_b = (const float*)d_in[6];
  const int*   cu     = (const int*)d_in[7];
  const int    ncu    = in_sizes[7];
  float* out = (float*)d_out;

  float* ws = (float*)d_ws;
  float* qkv_raw  = ws;                          // SEQ*NQKV f (63 MB)
  float* attn_out = ws + (size_t)SEQ * NQKV;     // SEQ*HIDN f (21 MB)

  // 1) QKV = hs @ qkv_w^T + qkv_b   (1-term bf16 MFMA)
  gemm_bf16<1><<<dim3(NQKV/128, SEQ/128), 256, 0, stream>>>(
      hs, qkv_w, qkv_b, qkv_raw, SEQ, NQKV, HIDN);
  // 2) RoPE in place on q,k
  {
    int tasks = SEQ * NHD * HLF;
    rope_inplace<<<(tasks + 255)/256, 256, 0, stream>>>(qkv_raw, cosb, sinb);
  }
  // 3) segment-blocked MFMA flash attention
  attn_mfma<<<dim3(SEQ/64, NHD), 256, 0, stream>>>(qkv_raw, cu, ncu, attn_out);
  // 4) out = attn_out @ proj_w^T + proj_b   (3-term compensated bf16 MFMA)
  gemm_bf16<3><<<dim3(HIDN/128, SEQ/128), 256, 0, stream>>>(
      attn_out, proj_w, proj_b, out, SEQ, HIDN, HIDN);
}

// Round 9
// 405.289 us; speedup vs baseline: 7.6884x; 1.4667x over previous
//
#include <hip/hip_runtime.h>
#include <hip/hip_bf16.h>

#define SEQ  4096
#define HIDN 1280
#define NHD  16
#define HDD  80
#define HLF  40
#define NQKV 3840

typedef __attribute__((ext_vector_type(8))) short short8v;  // 8 bf16 = 4 VGPR
typedef __attribute__((ext_vector_type(4))) float f32x4;
typedef unsigned short u16;
typedef unsigned int u32;

// round-to-nearest-even f32 -> bf16 bits
__device__ inline u16 f2b(float f) {
  union { float f; u32 u; } x; x.f = f;
  u32 r = x.u + 0x7fff + ((x.u >> 16) & 1);
  return (u16)(r >> 16);
}
// truncation split: v = hi + r, hi = top-16-bit truncation (exact sub), lo = bf16(r)
__device__ inline void split2(float v, u16& h, u16& l) {
  u32 u = __float_as_uint(v);
  h = (u16)(u >> 16);
  float r = v - __uint_as_float(u & 0xffff0000u);
  l = (u16)(__float_as_uint(r) >> 16);
}
// async global->LDS, 16B/lane. LDS dest = wave-uniform base + lane*16 (m104).
__device__ inline void glds16(const void* g, void* l) {
  __builtin_amdgcn_global_load_lds(
      (const __attribute__((address_space(1))) void*)g,
      (__attribute__((address_space(3))) void*)l, 16, 0, 0);
}

// =============================================================================
// fp32 -> bf16 (RNE), vectorized
// =============================================================================
__global__ __launch_bounds__(256) void to_bf16(
    const float* __restrict__ in, u16* __restrict__ out, int n4)
{
  int t = blockIdx.x * 256 + threadIdx.x;
  if (t >= n4) return;
  float4 v = *(const float4*)(in + 4 * (size_t)t);
  ushort4 b; b.x = f2b(v.x); b.y = f2b(v.y); b.z = f2b(v.z); b.w = f2b(v.w);
  *(ushort4*)(out + 4 * (size_t)t) = b;
}

// =============================================================================
// fp32 -> (hi,lo) bf16 split, vectorized
// =============================================================================
__global__ __launch_bounds__(256) void split_f32(
    const float* __restrict__ in, u16* __restrict__ oh, u16* __restrict__ ol,
    int n4)
{
  int t = blockIdx.x * 256 + threadIdx.x;
  if (t >= n4) return;
  float4 v = *(const float4*)(in + 4 * (size_t)t);
  ushort4 h, l;
  split2(v.x, h.x, l.x); split2(v.y, h.y, l.y);
  split2(v.z, h.z, l.z); split2(v.w, h.w, l.w);
  *(ushort4*)(oh + 4 * (size_t)t) = h;
  *(ushort4*)(ol + 4 * (size_t)t) = l;
}

// =============================================================================
// bf16 MFMA GEMM (NT) with global_load_lds staging + XOR chunk-swizzle.
// C[M][N] = A[M][K] @ W[N][K]^T + bias[N]; A,W pre-converted bf16.
// 128x128 tile, BK=64, 256 thr = 4 waves (2x2 grid, 64x64/wave).
// LDS tile [128][64] bf16 linear (glds needs linear dest); swizzle is applied
// on the GLOBAL source chunk at stage time and on the ds_read chunk at read
// time (involution: chunk ^ (row&7)) -> conflict-free b128 fragment reads
// (rule 21: both-sides-or-neither).
// TERMS=3: compensated hi/lo (ah*bh + al*bh + ah*bl), 4 LDS tiles, 64 KiB.
// launch_bounds 2nd arg = waves/EU = blocks/CU for 256-thr blocks.
// =============================================================================
template<int TERMS>
__global__ __launch_bounds__(256, TERMS == 3 ? 2 : 4) void gemm_glds(
    const u16* __restrict__ Ahg, const u16* __restrict__ Alg,
    const u16* __restrict__ Bhg, const u16* __restrict__ Blg,
    const float* __restrict__ bias, float* __restrict__ C,
    int M, int N, int K)
{
  constexpr bool COMP = (TERMS == 3);
  __shared__ u16 AhS[128 * 64];
  __shared__ u16 BhS[128 * 64];
  __shared__ u16 AlS[COMP ? 128 * 64 : 8];
  __shared__ u16 BlS[COMP ? 128 * 64 : 8];

  const int m0 = blockIdx.y * 128;
  const int n0 = blockIdx.x * 128;
  const int tid  = threadIdx.x;
  const int w    = tid >> 6;
  const int lane = tid & 63;
  const int ln   = lane & 15;
  const int lg   = lane >> 4;
  const int wr   = w >> 1;
  const int wc   = w & 1;
  // staging geometry: one glds covers a stripe of 8 rows x 64 bf16 (1024 B);
  // lane -> (sub-row ls, lds chunk lane&7); source chunk XOR-swizzled.
  const int ls = lane >> 3;
  const int lc = (lane & 7) ^ ls;

  f32x4 acc[4][4];
#pragma unroll
  for (int i = 0; i < 4; ++i)
#pragma unroll
    for (int j = 0; j < 4; ++j) acc[i][j] = (f32x4){0.f, 0.f, 0.f, 0.f};

  for (int k0 = 0; k0 < K; k0 += 64) {
    __syncthreads();                       // prev compute done before overwrite
    {
      const size_t abase = (size_t)m0 * K + k0;
      const size_t bbase = (size_t)n0 * K + k0;
#pragma unroll
      for (int st = 0; st < 4; ++st) {
        int stripe = w * 4 + st;           // wave-uniform
        size_t go = (size_t)(stripe * 8 + ls) * K + lc * 8;
        glds16(Ahg + abase + go, &AhS[stripe * 512]);
        glds16(Bhg + bbase + go, &BhS[stripe * 512]);
        if (COMP) {
          glds16(Alg + abase + go, &AlS[stripe * 512]);
          glds16(Blg + bbase + go, &BlS[stripe * 512]);
        }
      }
    }
    __syncthreads();                       // compiler drains vmcnt(0) before barrier

#pragma unroll
    for (int s = 0; s < 2; ++s) {
      short8v ah[4], bh[4], al[4], bl[4];
#pragma unroll
      for (int i = 0; i < 4; ++i) {
        int row = wr * 64 + i * 16 + ln;
        int ch  = ((s * 4 + lg) ^ (row & 7)) * 8;
        ah[i] = *(const short8v*)&AhS[row * 64 + ch];
        if (COMP) al[i] = *(const short8v*)&AlS[row * 64 + ch];
      }
#pragma unroll
      for (int j = 0; j < 4; ++j) {
        int row = wc * 64 + j * 16 + ln;
        int ch  = ((s * 4 + lg) ^ (row & 7)) * 8;
        bh[j] = *(const short8v*)&BhS[row * 64 + ch];
        if (COMP) bl[j] = *(const short8v*)&BlS[row * 64 + ch];
      }
#pragma unroll
      for (int i = 0; i < 4; ++i)
#pragma unroll
        for (int j = 0; j < 4; ++j) {
          acc[i][j] = __builtin_amdgcn_mfma_f32_16x16x32_bf16(ah[i], bh[j], acc[i][j], 0, 0, 0);
          if (COMP) {
            acc[i][j] = __builtin_amdgcn_mfma_f32_16x16x32_bf16(al[i], bh[j], acc[i][j], 0, 0, 0);
            acc[i][j] = __builtin_amdgcn_mfma_f32_16x16x32_bf16(ah[i], bl[j], acc[i][j], 0, 0, 0);
          }
        }
    }
  }

  float bj[4];
#pragma unroll
  for (int j = 0; j < 4; ++j) bj[j] = bias[n0 + wc * 64 + j * 16 + ln];
#pragma unroll
  for (int i = 0; i < 4; ++i) {
    int rowbase = m0 + wr * 64 + i * 16 + 4 * lg;
#pragma unroll
    for (int j = 0; j < 4; ++j) {
      int col = n0 + wc * 64 + j * 16 + ln;
#pragma unroll
      for (int q = 0; q < 4; ++q)
        C[(size_t)(rowbase + q) * N + col] = acc[i][j][q] + bj[j];
    }
  }
}

// =============================================================================
// RoPE in-place on qkv_raw[S][3][NH][HD] (q,k only) — unchanged.
// =============================================================================
__global__ __launch_bounds__(256) void rope_inplace(
    float* __restrict__ qkv, const float* __restrict__ cosb,
    const float* __restrict__ sinb)
{
  int t = blockIdx.x * 256 + threadIdx.x;
  if (t >= SEQ * NHD * HLF) return;
  int d = t % HLF;
  int h = (t / HLF) % NHD;
  int s = t / (HLF * NHD);

  size_t base = (size_t)s * NQKV + h * HDD;
  float q1 = qkv[base + d],          q2 = qkv[base + d + HLF];
  float k1 = qkv[base + HIDN + d],   k2 = qkv[base + HIDN + d + HLF];
  float c1 = cosb[(size_t)s*HDD + d], c2 = cosb[(size_t)s*HDD + d + HLF];
  float s1 = sinb[(size_t)s*HDD + d], s2 = sinb[(size_t)s*HDD + d + HLF];

  qkv[base + d]              = q1 * c1 - q2 * s1;
  qkv[base + d + HLF]        = q2 * c2 + q1 * s2;
  qkv[base + HIDN + d]       = k1 * c1 - k2 * s1;
  qkv[base + HIDN + d + HLF] = k2 * c2 + k1 * s2;
}

// =============================================================================
// bf16-MFMA flash attention (unchanged core); epilogue writes the hi/lo
// bf16 split of the output directly (feeds compensated proj GEMM).
// =============================================================================
__global__ __launch_bounds__(256) void attn_mfma(
    const float* __restrict__ qkv, const int* __restrict__ cu, int ncu,
    u16* __restrict__ aoh, u16* __restrict__ aol)
{
  __shared__ u16 Qs[64][104];
  __shared__ u16 Ks[64][104];
  __shared__ u16 Vt[80][72];      // [dim][krow]
  __shared__ u16 Pl[4][16][72];   // per-wave P, [qrow][kcol]

  const int h   = blockIdx.y;
  const int r0  = blockIdx.x * 64;
  const int tid = threadIdx.x;
  const int w    = tid >> 6;
  const int lane = tid & 63;
  const int lg   = lane >> 4;
  const int ln   = lane & 15;
  const float scale = 0.11180339887498949f;   // 80^-0.5

  for (int t = tid; t < 64*24; t += 256) {
    int row = t / 24, c = 80 + (t % 24);
    Qs[row][c] = 0; Ks[row][c] = 0;
  }
  for (int t = tid; t < 64*20; t += 256) {
    int row = t / 20, d4 = (t % 20) * 4;
    float4 v = *(const float4*)(qkv + (size_t)(r0+row)*NQKV + h*HDD + d4);
    ushort4 b; b.x = f2b(v.x); b.y = f2b(v.y); b.z = f2b(v.z); b.w = f2b(v.w);
    *(ushort4*)&Qs[row][d4] = b;
  }

  int lo[4], hi[4];
#pragma unroll
  for (int q = 0; q < 4; ++q) {
    int r = r0 + w*16 + 4*lg + q;
    int lo_ = 0, hi_ = SEQ;
    for (int j = 0; j + 1 < ncu; ++j)
      if (r >= cu[j] && r < cu[j+1]) { lo_ = cu[j]; hi_ = cu[j+1]; }
    lo[q] = lo_; hi[q] = hi_;
  }
  int klo = 0, khi = SEQ;
  for (int j = 0; j + 1 < ncu; ++j) {
    if (r0      >= cu[j] && r0      < cu[j+1]) klo = cu[j];
    if (r0 + 63 >= cu[j] && r0 + 63 < cu[j+1]) khi = cu[j+1];
  }

  f32x4 oacc[5];
#pragma unroll
  for (int vt = 0; vt < 5; ++vt) oacc[vt] = (f32x4){0.f,0.f,0.f,0.f};
  float m_[4] = {-3.0e38f,-3.0e38f,-3.0e38f,-3.0e38f};
  float l_[4] = {0.f,0.f,0.f,0.f};

  for (int kb = klo; kb < khi; kb += 64) {
    __syncthreads();
    for (int t = tid; t < 64*20; t += 256) {
      int row = t / 20, d4 = (t % 20) * 4;
      int gr = kb + row; if (gr > SEQ-1) gr = SEQ-1;
      float4 v = *(const float4*)(qkv + (size_t)gr*NQKV + h*HDD + HIDN + d4);
      ushort4 b; b.x = f2b(v.x); b.y = f2b(v.y); b.z = f2b(v.z); b.w = f2b(v.w);
      *(ushort4*)&Ks[row][d4] = b;
    }
    for (int t = tid; t < 64*20; t += 256) {
      int row = t & 63, d4 = (t >> 6) * 4;
      int gr = kb + row; if (gr > SEQ-1) gr = SEQ-1;
      float4 v = *(const float4*)(qkv + (size_t)gr*NQKV + h*HDD + 2*HIDN + d4);
      Vt[d4+0][row] = f2b(v.x);
      Vt[d4+1][row] = f2b(v.y);
      Vt[d4+2][row] = f2b(v.z);
      Vt[d4+3][row] = f2b(v.w);
    }
    __syncthreads();

    f32x4 sc[4];
#pragma unroll
    for (int n = 0; n < 4; ++n) sc[n] = (f32x4){0.f,0.f,0.f,0.f};
#pragma unroll
    for (int c = 0; c < 3; ++c) {
      short8v a = *(const short8v*)&Qs[w*16 + ln][c*32 + lg*8];
#pragma unroll
      for (int n = 0; n < 4; ++n) {
        short8v b = *(const short8v*)&Ks[n*16 + ln][c*32 + lg*8];
        sc[n] = __builtin_amdgcn_mfma_f32_16x16x32_bf16(a, b, sc[n], 0, 0, 0);
      }
    }

#pragma unroll
    for (int q = 0; q < 4; ++q) {
      float mx = -3.0e38f;
#pragma unroll
      for (int n = 0; n < 4; ++n) {
        int col = kb + n*16 + ln;
        bool valid = (col >= lo[q]) & (col < hi[q]);
        float s = valid ? sc[n][q] * scale : -3.0e38f;
        sc[n][q] = s;
        mx = fmaxf(mx, s);
      }
      mx = fmaxf(mx, __shfl_xor(mx, 1));
      mx = fmaxf(mx, __shfl_xor(mx, 2));
      mx = fmaxf(mx, __shfl_xor(mx, 4));
      mx = fmaxf(mx, __shfl_xor(mx, 8));
      float mnew = fmaxf(m_[q], mx);
      float alpha = __expf(m_[q] - mnew);
      float rs = 0.f;
#pragma unroll
      for (int n = 0; n < 4; ++n) {
        int col = kb + n*16 + ln;
        bool valid = (col >= lo[q]) & (col < hi[q]);
        float p = valid ? __expf(sc[n][q] - mnew) : 0.f;
        rs += p;
        Pl[w][4*lg + q][n*16 + ln] = f2b(p);
      }
      rs += __shfl_xor(rs, 1);
      rs += __shfl_xor(rs, 2);
      rs += __shfl_xor(rs, 4);
      rs += __shfl_xor(rs, 8);
      l_[q] = l_[q] * alpha + rs;
      m_[q] = mnew;
#pragma unroll
      for (int vt = 0; vt < 5; ++vt) oacc[vt][q] *= alpha;
    }
    __syncthreads();

#pragma unroll
    for (int c = 0; c < 2; ++c) {
      short8v a = *(const short8v*)&Pl[w][ln][c*32 + lg*8];
#pragma unroll
      for (int vt = 0; vt < 5; ++vt) {
        short8v b = *(const short8v*)&Vt[vt*16 + ln][c*32 + lg*8];
        oacc[vt] = __builtin_amdgcn_mfma_f32_16x16x32_bf16(a, b, oacc[vt], 0, 0, 0);
      }
    }
  }

  // epilogue: normalize, split to hi/lo bf16 for compensated proj
#pragma unroll
  for (int q = 0; q < 4; ++q) {
    float inv = 1.f / l_[q];
    size_t rowoff = (size_t)(r0 + w*16 + 4*lg + q) * HIDN + h * HDD;
#pragma unroll
    for (int vt = 0; vt < 5; ++vt) {
      float o = oacc[vt][q] * inv;
      u16 hh, ll; split2(o, hh, ll);
      aoh[rowoff + vt*16 + ln] = hh;
      aol[rowoff + vt*16 + ln] = ll;
    }
  }
}

// =============================================================================
// launch.  ws layout (83,886,080 B total — identical footprint to R5 proven):
//   [0, 63MB)        qkv_raw fp32        (live: gemm1 -> attn)
//                    then pwh/pwl bf16   (written after attn, live -> proj)
//   [63MB, 73.5MB)   hs_b bf16 (early) / aoh bf16 (late)
//   [73.5MB, 80MB)   qkv_wb bf16 (early) / aol bf16 (late, +0.65MB tail)
// =============================================================================
extern "C" void kernel_launch(void* const* d_in, const int* in_sizes, int n_in,
                              void* d_out, int out_size, void* d_ws, size_t ws_size,
                              hipStream_t stream) {
  const float* hs     = (const float*)d_in[0];
  const float* cosb   = (const float*)d_in[1];
  const float* sinb   = (const float*)d_in[2];
  const float* qkv_w  = (const float*)d_in[3];
  const float* qkv_b  = (const float*)d_in[4];
  const float* proj_w = (const float*)d_in[5];
  const float* proj_b = (const float*)d_in[6];
  const int*   cu     = (const int*)d_in[7];
  const int    ncu    = in_sizes[7];
  float* out = (float*)d_out;

  char* wsb = (char*)d_ws;
  float* qkv_raw = (float*)wsb;                               // 62,914,560 B
  u16* pwh    = (u16*)wsb;                                    // reuse after attn
  u16* pwl    = (u16*)(wsb + 3276800);
  u16* hs_b   = (u16*)(wsb + 62914560);                       // early
  u16* qkv_wb = (u16*)(wsb + 62914560 + 10485760);            // early
  u16* aoh    = (u16*)(wsb + 62914560);                       // late (hs_b dead)
  u16* aol    = (u16*)(wsb + 62914560 + 10485760);            // late (qkv_wb dead)

  // 0) pre-convert GEMM1 operands to bf16
  to_bf16<<<(SEQ*HIDN/4 + 255)/256, 256, 0, stream>>>(hs, hs_b, SEQ*HIDN/4);
  to_bf16<<<(NQKV*HIDN/4 + 255)/256, 256, 0, stream>>>(qkv_w, qkv_wb, NQKV*HIDN/4);
  // 1) QKV = hs @ qkv_w^T + qkv_b   (1-term bf16, glds staging)
  gemm_glds<1><<<dim3(NQKV/128, SEQ/128), 256, 0, stream>>>(
      hs_b, nullptr, qkv_wb, nullptr, qkv_b, qkv_raw, SEQ, NQKV, HIDN);
  // 2) RoPE in place on q,k
  rope_inplace<<<(SEQ*NHD*HLF + 255)/256, 256, 0, stream>>>(qkv_raw, cosb, sinb);
  // 3) segment-blocked MFMA flash attention -> aoh/aol (hi/lo split)
  attn_mfma<<<dim3(SEQ/64, NHD), 256, 0, stream>>>(qkv_raw, cu, ncu, aoh, aol);
  // 4) split proj_w into (pwh, pwl) in the now-dead qkv_raw region
  split_f32<<<(HIDN*HIDN/4 + 255)/256, 256, 0, stream>>>(proj_w, pwh, pwl, HIDN*HIDN/4);
  // 5) out = attn_out @ proj_w^T + proj_b   (3-term compensated, glds staging)
  gemm_glds<3><<<dim3(HIDN/128, SEQ/128), 256, 0, stream>>>(
      aoh, aol, pwh, pwl, proj_b, out, SEQ, HIDN, HIDN);
}

// Round 13
// 311.717 us; speedup vs baseline: 9.9964x; 1.3002x over previous
//
#include <hip/hip_runtime.h>
#include <hip/hip_bf16.h>

#define SEQ  4096
#define HIDN 1280
#define NHD  16
#define HDD  80
#define HLF  40
#define NQKV 3840

typedef __attribute__((ext_vector_type(8))) short short8v;  // 8 bf16 = 4 VGPR
typedef __attribute__((ext_vector_type(4))) float f32x4;
typedef unsigned short u16;
typedef unsigned int u32;

// round-to-nearest-even f32 -> bf16 bits
__device__ inline u16 f2b(float f) {
  union { float f; u32 u; } x; x.f = f;
  u32 r = x.u + 0x7fff + ((x.u >> 16) & 1);
  return (u16)(r >> 16);
}
// truncation split: v = hi + r, hi = top-16-bit truncation (exact sub), lo = bf16(r)
__device__ inline void split2(float v, u16& h, u16& l) {
  u32 u = __float_as_uint(v);
  h = (u16)(u >> 16);
  float r = v - __uint_as_float(u & 0xffff0000u);
  l = (u16)(__float_as_uint(r) >> 16);
}
// async global->LDS, 16B/lane. LDS dest = wave-uniform base + lane*16 (m104).
__device__ inline void glds16(const void* g, void* l) {
  __builtin_amdgcn_global_load_lds(
      (const __attribute__((address_space(1))) void*)g,
      (__attribute__((address_space(3))) void*)l, 16, 0, 0);
}

// =============================================================================
// fp32 -> bf16 (RNE), vectorized
// =============================================================================
__global__ __launch_bounds__(256) void to_bf16(
    const float* __restrict__ in, u16* __restrict__ out, int n4)
{
  int t = blockIdx.x * 256 + threadIdx.x;
  if (t >= n4) return;
  float4 v = *(const float4*)(in + 4 * (size_t)t);
  ushort4 b; b.x = f2b(v.x); b.y = f2b(v.y); b.z = f2b(v.z); b.w = f2b(v.w);
  *(ushort4*)(out + 4 * (size_t)t) = b;
}

// =============================================================================
// fp32 -> (hi,lo) bf16 split, vectorized
// =============================================================================
__global__ __launch_bounds__(256) void split_f32(
    const float* __restrict__ in, u16* __restrict__ oh, u16* __restrict__ ol,
    int n4)
{
  int t = blockIdx.x * 256 + threadIdx.x;
  if (t >= n4) return;
  float4 v = *(const float4*)(in + 4 * (size_t)t);
  ushort4 h, l;
  split2(v.x, h.x, l.x); split2(v.y, h.y, l.y);
  split2(v.z, h.z, l.z); split2(v.w, h.w, l.w);
  *(ushort4*)(oh + 4 * (size_t)t) = h;
  *(ushort4*)(ol + 4 * (size_t)t) = l;
}

// =============================================================================
// bf16 MFMA GEMM (NT) with global_load_lds staging + XOR chunk-swizzle.
// (unchanged from R9 — validated: gemm1 no longer top dispatch)
// =============================================================================
template<int TERMS>
__global__ __launch_bounds__(256, TERMS == 3 ? 2 : 4) void gemm_glds(
    const u16* __restrict__ Ahg, const u16* __restrict__ Alg,
    const u16* __restrict__ Bhg, const u16* __restrict__ Blg,
    const float* __restrict__ bias, float* __restrict__ C,
    int M, int N, int K)
{
  constexpr bool COMP = (TERMS == 3);
  __shared__ u16 AhS[128 * 64];
  __shared__ u16 BhS[128 * 64];
  __shared__ u16 AlS[COMP ? 128 * 64 : 8];
  __shared__ u16 BlS[COMP ? 128 * 64 : 8];

  const int m0 = blockIdx.y * 128;
  const int n0 = blockIdx.x * 128;
  const int tid  = threadIdx.x;
  const int w    = tid >> 6;
  const int lane = tid & 63;
  const int ln   = lane & 15;
  const int lg   = lane >> 4;
  const int wr   = w >> 1;
  const int wc   = w & 1;
  const int ls = lane >> 3;
  const int lc = (lane & 7) ^ ls;

  f32x4 acc[4][4];
#pragma unroll
  for (int i = 0; i < 4; ++i)
#pragma unroll
    for (int j = 0; j < 4; ++j) acc[i][j] = (f32x4){0.f, 0.f, 0.f, 0.f};

  for (int k0 = 0; k0 < K; k0 += 64) {
    __syncthreads();
    {
      const size_t abase = (size_t)m0 * K + k0;
      const size_t bbase = (size_t)n0 * K + k0;
#pragma unroll
      for (int st = 0; st < 4; ++st) {
        int stripe = w * 4 + st;
        size_t go = (size_t)(stripe * 8 + ls) * K + lc * 8;
        glds16(Ahg + abase + go, &AhS[stripe * 512]);
        glds16(Bhg + bbase + go, &BhS[stripe * 512]);
        if (COMP) {
          glds16(Alg + abase + go, &AlS[stripe * 512]);
          glds16(Blg + bbase + go, &BlS[stripe * 512]);
        }
      }
    }
    __syncthreads();

#pragma unroll
    for (int s = 0; s < 2; ++s) {
      short8v ah[4], bh[4], al[4], bl[4];
#pragma unroll
      for (int i = 0; i < 4; ++i) {
        int row = wr * 64 + i * 16 + ln;
        int ch  = ((s * 4 + lg) ^ (row & 7)) * 8;
        ah[i] = *(const short8v*)&AhS[row * 64 + ch];
        if (COMP) al[i] = *(const short8v*)&AlS[row * 64 + ch];
      }
#pragma unroll
      for (int j = 0; j < 4; ++j) {
        int row = wc * 64 + j * 16 + ln;
        int ch  = ((s * 4 + lg) ^ (row & 7)) * 8;
        bh[j] = *(const short8v*)&BhS[row * 64 + ch];
        if (COMP) bl[j] = *(const short8v*)&BlS[row * 64 + ch];
      }
#pragma unroll
      for (int i = 0; i < 4; ++i)
#pragma unroll
        for (int j = 0; j < 4; ++j) {
          acc[i][j] = __builtin_amdgcn_mfma_f32_16x16x32_bf16(ah[i], bh[j], acc[i][j], 0, 0, 0);
          if (COMP) {
            acc[i][j] = __builtin_amdgcn_mfma_f32_16x16x32_bf16(al[i], bh[j], acc[i][j], 0, 0, 0);
            acc[i][j] = __builtin_amdgcn_mfma_f32_16x16x32_bf16(ah[i], bl[j], acc[i][j], 0, 0, 0);
          }
        }
    }
  }

  float bj[4];
#pragma unroll
  for (int j = 0; j < 4; ++j) bj[j] = bias[n0 + wc * 64 + j * 16 + ln];
#pragma unroll
  for (int i = 0; i < 4; ++i) {
    int rowbase = m0 + wr * 64 + i * 16 + 4 * lg;
#pragma unroll
    for (int j = 0; j < 4; ++j) {
      int col = n0 + wc * 64 + j * 16 + ln;
#pragma unroll
      for (int q = 0; q < 4; ++q)
        C[(size_t)(rowbase + q) * N + col] = acc[i][j][q] + bj[j];
    }
  }
}

// =============================================================================
// Fused RoPE + bf16 convert + V-transpose.
// Block = (head h, 64-row s-tile). Reads qkv_raw fp32; writes:
//   q_bf[h][s][d], k_bf[h][s][d]  (roped, bf16, coalesced rows)
//   vt_bf[h][d][s]                (bf16, globally transposed via LDS)
// After this kernel qkv_raw is DEAD — attention touches only bf16 planes.
// Known minor cost (audited R12): transposed vtL writes are ~8-way bank
// conflicted; bounded ~10us on a one-shot kernel; padding would break the
// 16B alignment needed by b128 reads, so left as-is.
// =============================================================================
__global__ __launch_bounds__(256) void rope2_convert(
    const float* __restrict__ qkv, const float* __restrict__ cosb,
    const float* __restrict__ sinb,
    u16* __restrict__ qb, u16* __restrict__ kb,
    u16* __restrict__ vtb)
{
  __shared__ u16 vtL[80][72];
  const int h  = blockIdx.y;
  const int s0 = blockIdx.x * 64;
  const int tid = threadIdx.x;

  // V: 64s x 80d fp32 -> bf16 transposed into LDS (1280 float4 tasks)
  for (int t = tid; t < 1280; t += 256) {
    int s = t / 20, d4 = (t % 20) * 4;
    float4 v = *(const float4*)(qkv + (size_t)(s0 + s) * NQKV + 2*HIDN + h*HDD + d4);
    vtL[d4+0][s] = f2b(v.x);
    vtL[d4+1][s] = f2b(v.y);
    vtL[d4+2][s] = f2b(v.z);
    vtL[d4+3][s] = f2b(v.w);
  }
  // q,k: RoPE + convert (2560 pair tasks)
  for (int t = tid; t < 2560; t += 256) {
    int s = t / 40, d = t % 40;
    size_t base = (size_t)(s0 + s) * NQKV + h * HDD;
    float q1 = qkv[base + d],        q2 = qkv[base + d + HLF];
    float k1 = qkv[base + HIDN + d], k2 = qkv[base + HIDN + d + HLF];
    float c1 = cosb[(size_t)(s0+s)*HDD + d], c2 = cosb[(size_t)(s0+s)*HDD + d + HLF];
    float s1 = sinb[(size_t)(s0+s)*HDD + d], s2 = sinb[(size_t)(s0+s)*HDD + d + HLF];
    size_t ob = ((size_t)h * SEQ + s0 + s) * HDD;
    qb[ob + d]       = f2b(q1 * c1 - q2 * s1);
    qb[ob + d + HLF] = f2b(q2 * c2 + q1 * s2);
    kb[ob + d]       = f2b(k1 * c1 - k2 * s1);
    kb[ob + d + HLF] = f2b(k2 * c2 + k1 * s2);
  }
  __syncthreads();
  // Vt out: [NH][80][SEQ], 640 b128 chunks, coalesced 128B runs
  for (int t = tid; t < 640; t += 256) {
    int d = t >> 3, cp = t & 7;
    short8v v = *(const short8v*)&vtL[d][cp * 8];
    *(short8v*)(vtb + ((size_t)h * HDD + d) * SEQ + s0 + cp * 8) = v;
  }
}

// =============================================================================
// bf16-MFMA flash attention v2.
// Q: direct global fragment loads (once per block, reused all tiles).
// K: direct global fragment loads per tile (L2-resident via XCD swizzle).
// V: b128-staged from pre-transposed vt_bf. Pl per-wave (no barrier).
// LDS 20.3 KB -> occupancy no longer LDS-limited. 2 barriers/tile.
// Grid: 1024 linear, XCD-swizzled so each XCD owns 2 heads (K/V L2 locality).
// =============================================================================
__global__ __launch_bounds__(256) void attn_mfma2(
    const u16* __restrict__ qb, const u16* __restrict__ kbp,
    const u16* __restrict__ vtb, const int* __restrict__ cu, int ncu,
    u16* __restrict__ aoh, u16* __restrict__ aol)
{
  __shared__ u16 Vt[80][72];      // [dim][krow]
  __shared__ u16 Pl[4][16][72];   // per-wave P, [qrow][kcol]

  // XCD-aware swizzle (1024 blocks, 1024%8==0 -> simple form is bijective)
  const int orig = blockIdx.x;
  const int wgid = (orig & 7) * 128 + (orig >> 3);
  const int h  = wgid >> 6;
  const int r0 = (wgid & 63) * 64;

  const int tid = threadIdx.x;
  const int w    = tid >> 6;
  const int lane = tid & 63;
  const int lg   = lane >> 4;
  const int ln   = lane & 15;
  const float scale = 0.11180339887498949f;   // 80^-0.5
  const short8v zero8 = {0,0,0,0,0,0,0,0};

  // Q fragments: 3 direct 16B loads, reused across all K-tiles.
  // A-frag map: row = r0+w*16+ln, k-dim = c*32+lg*8+j (c=2,lg>=2 is pad->0)
  const u16* qrow = qb + ((size_t)h * SEQ + r0 + w*16 + ln) * HDD;
  short8v qa[3];
  qa[0] = *(const short8v*)(qrow + lg*8);
  qa[1] = *(const short8v*)(qrow + 32 + lg*8);
  qa[2] = (lg < 2) ? *(const short8v*)(qrow + 64 + lg*8) : zero8;

  // segment bounds
  int lo[4], hi[4];
#pragma unroll
  for (int q = 0; q < 4; ++q) {
    int r = r0 + w*16 + 4*lg + q;
    int lo_ = 0, hi_ = SEQ;
    for (int j = 0; j + 1 < ncu; ++j)
      if (r >= cu[j] && r < cu[j+1]) { lo_ = cu[j]; hi_ = cu[j+1]; }
    lo[q] = lo_; hi[q] = hi_;
  }
  int klo = 0, khi = SEQ;
  for (int j = 0; j + 1 < ncu; ++j) {
    if (r0      >= cu[j] && r0      < cu[j+1]) klo = cu[j];
    if (r0 + 63 >= cu[j] && r0 + 63 < cu[j+1]) khi = cu[j+1];
  }

  f32x4 oacc[5];
#pragma unroll
  for (int vt = 0; vt < 5; ++vt) oacc[vt] = (f32x4){0.f,0.f,0.f,0.f};
  float m_[4] = {-3.0e38f,-3.0e38f,-3.0e38f,-3.0e38f};
  float l_[4] = {0.f,0.f,0.f,0.f};

  for (int kb = klo; kb < khi; kb += 64) {
    __syncthreads();   // prev PV reads of Vt done
    // stage Vt from pre-transposed global: 640 b128 chunks, no conversion
    for (int t = tid; t < 640; t += 256) {
      int d = t >> 3, cp = t & 7;
      short8v v = *(const short8v*)(vtb + ((size_t)h * HDD + d) * SEQ + kb + cp*8);
      *(short8v*)&Vt[d][cp * 8] = v;
    }
    __syncthreads();

    // ---- QK^T: K B-frags direct from global (L2-hot) ----
    f32x4 sc[4];
#pragma unroll
    for (int n = 0; n < 4; ++n) sc[n] = (f32x4){0.f,0.f,0.f,0.f};
#pragma unroll
    for (int c = 0; c < 3; ++c) {
#pragma unroll
      for (int n = 0; n < 4; ++n) {
        const u16* krow = kbp + ((size_t)h * SEQ + kb + n*16 + ln) * HDD;
        short8v b = (c < 2 || lg < 2) ? *(const short8v*)(krow + c*32 + lg*8) : zero8;
        sc[n] = __builtin_amdgcn_mfma_f32_16x16x32_bf16(qa[c], b, sc[n], 0, 0, 0);
      }
    }

    // ---- online softmax (rows 4*lg+q live in this 16-lane group) ----
#pragma unroll
    for (int q = 0; q < 4; ++q) {
      float mx = -3.0e38f;
#pragma unroll
      for (int n = 0; n < 4; ++n) {
        int col = kb + n*16 + ln;
        bool valid = (col >= lo[q]) & (col < hi[q]);
        float s = valid ? sc[n][q] * scale : -3.0e38f;
        sc[n][q] = s;
        mx = fmaxf(mx, s);
      }
      mx = fmaxf(mx, __shfl_xor(mx, 1));
      mx = fmaxf(mx, __shfl_xor(mx, 2));
      mx = fmaxf(mx, __shfl_xor(mx, 4));
      mx = fmaxf(mx, __shfl_xor(mx, 8));
      float mnew = fmaxf(m_[q], mx);
      float alpha = __expf(m_[q] - mnew);
      float rs = 0.f;
#pragma unroll
      for (int n = 0; n < 4; ++n) {
        int col = kb + n*16 + ln;
        bool valid = (col >= lo[q]) & (col < hi[q]);
        float p = valid ? __expf(sc[n][q] - mnew) : 0.f;
        rs += p;
        Pl[w][4*lg + q][n*16 + ln] = f2b(p);
      }
      rs += __shfl_xor(rs, 1);
      rs += __shfl_xor(rs, 2);
      rs += __shfl_xor(rs, 4);
      rs += __shfl_xor(rs, 8);
      l_[q] = l_[q] * alpha + rs;
      m_[q] = mnew;
#pragma unroll
      for (int vt = 0; vt < 5; ++vt) oacc[vt][q] *= alpha;
    }
    // no barrier: Pl is per-wave (compiler orders ds_write->ds_read)

    // ---- PV ----
#pragma unroll
    for (int c = 0; c < 2; ++c) {
      short8v a = *(const short8v*)&Pl[w][ln][c*32 + lg*8];
#pragma unroll
      for (int vt = 0; vt < 5; ++vt) {
        short8v b = *(const short8v*)&Vt[vt*16 + ln][c*32 + lg*8];
        oacc[vt] = __builtin_amdgcn_mfma_f32_16x16x32_bf16(a, b, oacc[vt], 0, 0, 0);
      }
    }
  }

  // epilogue: normalize, hi/lo split for compensated proj
#pragma unroll
  for (int q = 0; q < 4; ++q) {
    float inv = 1.f / l_[q];
    size_t rowoff = (size_t)(r0 + w*16 + 4*lg + q) * HIDN + h * HDD;
#pragma unroll
    for (int vt = 0; vt < 5; ++vt) {
      float o = oacc[vt][q] * inv;
      u16 hh, ll; split2(o, hh, ll);
      aoh[rowoff + vt*16 + ln] = hh;
      aol[rowoff + vt*16 + ln] = ll;
    }
  }
}

// =============================================================================
// launch. ws layout (115,343,360 B used; <=126 MB proven in R2/R3):
//   [0,   63.0M)  qkv_raw fp32 (gemm1 -> rope2), then pwh/pwl (after rope2)
//   [63.0, 73.4M) hs_b early  -> q_bf late
//   [73.4, 83.9M) qkv_wb early -> k_bf late
//   [83.9, 94.4M) vt_bf
//   [94.4,104.9M) aoh
//   [104.9,115.3M) aol
// =============================================================================
extern "C" void kernel_launch(void* const* d_in, const int* in_sizes, int n_in,
                              void* d_out, int out_size, void* d_ws, size_t ws_size,
                              hipStream_t stream) {
  const float* hs     = (const float*)d_in[0];
  const float* cosb   = (const float*)d_in[1];
  const float* sinb   = (const float*)d_in[2];
  const float* qkv_w  = (const float*)d_in[3];
  const float* qkv_b  = (const float*)d_in[4];
  const float* proj_w = (const float*)d_in[5];
  const float* proj_b = (const float*)d_in[6];
  const int*   cu     = (const int*)d_in[7];
  const int    ncu    = in_sizes[7];
  float* out = (float*)d_out;

  char* wsb = (char*)d_ws;
  float* qkv_raw = (float*)wsb;                     // 62,914,560 B
  u16* pwh    = (u16*)wsb;                          // after rope2 (qkv_raw dead)
  u16* pwl    = (u16*)(wsb + 3276800);
  u16* hs_b   = (u16*)(wsb + 62914560);             // early
  u16* qkv_wb = (u16*)(wsb + 73400320);             // early
  u16* q_bf   = (u16*)(wsb + 62914560);             // late (hs_b dead)
  u16* k_bf   = (u16*)(wsb + 73400320);             // late (qkv_wb dead)
  u16* vt_bf  = (u16*)(wsb + 83886080);
  u16* aoh    = (u16*)(wsb + 94371840);
  u16* aol    = (u16*)(wsb + 104857600);

  // 0) pre-convert GEMM1 operands to bf16
  to_bf16<<<(SEQ*HIDN/4 + 255)/256, 256, 0, stream>>>(hs, hs_b, SEQ*HIDN/4);
  to_bf16<<<(NQKV*HIDN/4 + 255)/256, 256, 0, stream>>>(qkv_w, qkv_wb, NQKV*HIDN/4);
  // 1) QKV = hs @ qkv_w^T + qkv_b
  gemm_glds<1><<<dim3(NQKV/128, SEQ/128), 256, 0, stream>>>(
      hs_b, nullptr, qkv_wb, nullptr, qkv_b, qkv_raw, SEQ, NQKV, HIDN);
  // 2) fused RoPE + bf16 planes + V transpose
  rope2_convert<<<dim3(SEQ/64, NHD), 256, 0, stream>>>(
      qkv_raw, cosb, sinb, q_bf, k_bf, vt_bf);
  // 3) flash attention v2 (XCD-swizzled linear grid)
  attn_mfma2<<<(SEQ/64) * NHD, 256, 0, stream>>>(
      q_bf, k_bf, vt_bf, cu, ncu, aoh, aol);
  // 4) split proj_w (qkv_raw region is dead now)
  split_f32<<<(HIDN*HIDN/4 + 255)/256, 256, 0, stream>>>(proj_w, pwh, pwl, HIDN*HIDN/4);
  // 5) out = attn_out @ proj_w^T + proj_b (3-term compensated)
  gemm_glds<3><<<dim3(HIDN/128, SEQ/128), 256, 0, stream>>>(
      aoh, aol, pwh, pwl, proj_b, out, SEQ, HIDN, HIDN);
}